// Round 1
// baseline (94.584 us; speedup 1.0000x reference)
//
#include <hip/hip_runtime.h>

#define HH 64
#define WW 96
#define DD 64
#define VV 4
#define CC 16
#define HW (HH*WW)
#define EPSF 1e-8f

// ---------------------------------------------------------------------------
// Transpose: src (V,C,HW) -> srcT (V,HW,C); cur (C,HW) -> curT (HW,C)
// Reads coalesced (tid walks input linearly); writes are 64B-chunk scattered
// but the whole thing is ~2 MB so it's a couple of microseconds at worst.
// ---------------------------------------------------------------------------
__global__ __launch_bounds__(256) void cv_transpose_kernel(
    const float* __restrict__ src, const float* __restrict__ cur,
    float* __restrict__ srcT, float* __restrict__ curT)
{
    int tid = blockIdx.x * blockDim.x + threadIdx.x;
    const int total_src = VV * CC * HW;
    if (tid < total_src) {
        int v   = tid / (CC * HW);
        int rem = tid - v * (CC * HW);
        int c   = rem / HW;
        int hw  = rem - c * HW;
        srcT[(size_t)(v * HW + hw) * CC + c] = src[tid];
    } else {
        int t = tid - total_src;
        if (t < CC * HW) {
            int c  = t / HW;
            int hw = t - c * HW;
            curT[(size_t)hw * CC + c] = cur[t];
        }
    }
}

// ---------------------------------------------------------------------------
// Main fused kernel: projection + bilinear grid-sample + channel dot + view sum
// One thread per output element (d, h, w).
// TRANS=true : curF is (HW,C), srcF is (V,HW,C)  (transposed, float4 taps)
// TRANS=false: curF is (C,HW), srcF is (V,C,HW)  (original layout fallback)
// ---------------------------------------------------------------------------
template<bool TRANS>
__global__ __launch_bounds__(256) void cost_volume_kernel(
    const float* __restrict__ curF,
    const float* __restrict__ srcF,
    const float* __restrict__ extr,   // (V,4,4)
    const float* __restrict__ Ks,     // (V,4,4)
    const float* __restrict__ invK,   // (4,4)
    const float* __restrict__ min_d,
    const float* __restrict__ max_d,
    float* __restrict__ out)          // (D,HW)
{
    // P[v] = (K[v] @ E[v])[:3, :]  -- 12 floats per view, computed once per block
    __shared__ float P_s[VV * 12];
    {
        int t = threadIdx.x;
        if (t < VV * 12) {
            int v   = t / 12;
            int r   = (t % 12) / 4;
            int col = t % 4;
            float s = 0.f;
            #pragma unroll
            for (int k = 0; k < 4; ++k)
                s += Ks[v * 16 + r * 4 + k] * extr[v * 16 + k * 4 + col];
            P_s[t] = s;
        }
    }
    __syncthreads();

    int tid = blockIdx.x * blockDim.x + threadIdx.x;
    if (tid >= DD * HW) return;
    int d  = tid / HW;
    int hw = tid - d * HW;
    int h  = hw / WW;
    int w  = hw - h * WW;

    // ray = invK[:3,:3] @ (w+0.5, h+0.5, 1)   (invK uniform -> scalar loads)
    float px = (float)w + 0.5f, py = (float)h + 0.5f;
    float rx = invK[0] * px + invK[1] * py + invK[2];
    float ry = invK[4] * px + invK[5] * py + invK[6];
    float rz = invK[8] * px + invK[9] * py + invK[10];

    float inv_min = 1.f / min_d[0];
    float inv_max = 1.f / max_d[0];
    float depth   = 1.f / (inv_min + (inv_max - inv_min) * ((float)d / (float)(DD - 1)));

    // current-frame feature vector for this pixel
    float cf[CC];
    if (TRANS) {
        const float4* p = (const float4*)(curF + (size_t)hw * CC);
        #pragma unroll
        for (int i = 0; i < CC / 4; ++i) {
            float4 q = p[i];
            cf[4*i+0] = q.x; cf[4*i+1] = q.y; cf[4*i+2] = q.z; cf[4*i+3] = q.w;
        }
    } else {
        #pragma unroll
        for (int c = 0; c < CC; ++c) cf[c] = curF[c * HW + hw];
    }

    float acc = 0.f;
    #pragma unroll
    for (int v = 0; v < VV; ++v) {
        const float* P = &P_s[v * 12];
        float cx = depth * (P[0] * rx + P[1] * ry + P[2]  * rz) + P[3];
        float cy = depth * (P[4] * rx + P[5] * ry + P[6]  * rz) + P[7];
        float cz = depth * (P[8] * rx + P[9] * ry + P[10] * rz) + P[11];
        if (cz > 0.f) {
            float iz = 1.f / (cz + EPSF);
            float x = cx * iz - 0.5f;
            float y = cy * iz - 0.5f;
            float x0f = floorf(x), y0f = floorf(y);
            float fx = x - x0f, fy = y - y0f;
            float x1f = x0f + 1.f, y1f = y0f + 1.f;
            // clamp in float first (avoids int overflow on wild projections)
            int ix0 = (int)fminf(fmaxf(x0f, 0.f), (float)(WW - 1));
            int ix1 = (int)fminf(fmaxf(x1f, 0.f), (float)(WW - 1));
            int iy0 = (int)fminf(fmaxf(y0f, 0.f), (float)(HH - 1));
            int iy1 = (int)fminf(fmaxf(y1f, 0.f), (float)(HH - 1));
            bool vx0 = (x0f >= 0.f) && (x0f < (float)WW);
            bool vx1 = (x1f >= 0.f) && (x1f < (float)WW);
            bool vy0 = (y0f >= 0.f) && (y0f < (float)HH);
            bool vy1 = (y1f >= 0.f) && (y1f < (float)HH);
            float w00 = (vx0 && vy0) ? (1.f - fx) * (1.f - fy) : 0.f;
            float w01 = (vx1 && vy0) ? fx * (1.f - fy) : 0.f;   // (x0+1, y0)
            float w10 = (vx0 && vy1) ? (1.f - fx) * fy : 0.f;   // (x0,   y0+1)
            float w11 = (vx1 && vy1) ? fx * fy : 0.f;

            float d00, d01, d10, d11;
            if (TRANS) {
                auto tap = [&](int iy, int ix) -> float {
                    const float4* p = (const float4*)(srcF + (size_t)((v * HW) + iy * WW + ix) * CC);
                    float s = 0.f;
                    #pragma unroll
                    for (int i = 0; i < CC / 4; ++i) {
                        float4 q = p[i];
                        s += q.x * cf[4*i+0] + q.y * cf[4*i+1] + q.z * cf[4*i+2] + q.w * cf[4*i+3];
                    }
                    return s;
                };
                d00 = tap(iy0, ix0);
                d01 = tap(iy0, ix1);
                d10 = tap(iy1, ix0);
                d11 = tap(iy1, ix1);
            } else {
                d00 = d01 = d10 = d11 = 0.f;
                int b = v * CC * HW;
                int i00 = iy0 * WW + ix0, i01 = iy0 * WW + ix1;
                int i10 = iy1 * WW + ix0, i11 = iy1 * WW + ix1;
                #pragma unroll
                for (int c = 0; c < CC; ++c) {
                    const float* fc = srcF + b + c * HW;
                    d00 += fc[i00] * cf[c];
                    d01 += fc[i01] * cf[c];
                    d10 += fc[i10] * cf[c];
                    d11 += fc[i11] * cf[c];
                }
            }
            acc += w00 * d00 + w01 * d01 + w10 * d10 + w11 * d11;
        }
    }
    out[tid] = acc;
}

extern "C" void kernel_launch(void* const* d_in, const int* in_sizes, int n_in,
                              void* d_out, int out_size, void* d_ws, size_t ws_size,
                              hipStream_t stream) {
    const float* cur  = (const float*)d_in[0];  // (1,C,H,W)
    const float* src  = (const float*)d_in[1];  // (1,V,C,H,W)
    const float* extr = (const float*)d_in[2];  // (1,V,4,4)
    const float* Ks   = (const float*)d_in[3];  // (1,V,4,4)
    const float* invK = (const float*)d_in[4];  // (1,4,4)
    const float* mind = (const float*)d_in[5];
    const float* maxd = (const float*)d_in[6];
    float* out = (float*)d_out;                 // (1,D,H,W)

    const size_t need = (size_t)(VV * HW * CC + HW * CC) * sizeof(float);
    const int n_out = DD * HW;
    const int blocks = (n_out + 255) / 256;

    if (ws_size >= need) {
        float* srcT = (float*)d_ws;
        float* curT = srcT + (size_t)VV * HW * CC;
        const int total = VV * CC * HW + CC * HW;
        cv_transpose_kernel<<<(total + 255) / 256, 256, 0, stream>>>(src, cur, srcT, curT);
        cost_volume_kernel<true><<<blocks, 256, 0, stream>>>(
            curT, srcT, extr, Ks, invK, mind, maxd, out);
    } else {
        cost_volume_kernel<false><<<blocks, 256, 0, stream>>>(
            cur, src, extr, Ks, invK, mind, maxd, out);
    }
}

// Round 2
// 79.938 us; speedup vs baseline: 1.1832x; 1.1832x over previous
//
#include <hip/hip_runtime.h>
#include <hip/hip_fp16.h>

#define HH 64
#define WW 96
#define DD 64
#define VV 4
#define CC 16
#define HW (HH*WW)
#define EPSF 1e-8f

// ---------------------------------------------------------------------------
// Pack kernel: src (V,C,HW) fp32 -> srcT (V,HW,C) fp16 ; cur (C,HW) -> curT (HW,C) fp32
// One thread per pixel: channel reads coalesced across lanes (fixed c,
// consecutive hw), writes contiguous 32B (fp16) / 64B (fp32) per thread.
// ---------------------------------------------------------------------------
__global__ __launch_bounds__(256) void cv_pack_kernel(
    const float* __restrict__ src, const float* __restrict__ cur,
    __half* __restrict__ srcT, float* __restrict__ curT)
{
    int tid = blockIdx.x * blockDim.x + threadIdx.x;
    if (tid < VV * HW) {
        int v  = tid / HW;
        int hw = tid - v * HW;
        unsigned short pk[CC];
        #pragma unroll
        for (int c = 0; c < CC; ++c) {
            float f = src[(size_t)v * CC * HW + c * HW + hw];
            pk[c] = __half_as_ushort(__float2half(f));
        }
        uint4* dst = (uint4*)(srcT + (size_t)tid * CC);
        dst[0] = *(uint4*)&pk[0];
        dst[1] = *(uint4*)&pk[8];
    } else {
        int hw = tid - VV * HW;
        if (hw < HW) {
            float buf[CC];
            #pragma unroll
            for (int c = 0; c < CC; ++c) buf[c] = cur[c * HW + hw];
            float4* dst = (float4*)(curT + (size_t)hw * CC);
            #pragma unroll
            for (int i = 0; i < 4; ++i) dst[i] = *(float4*)&buf[4 * i];
        }
    }
}

// 32B fp16 tap dot with fp32 cf / fp32 accumulate
__device__ __forceinline__ float tap_dot16(const __half* __restrict__ p,
                                           const float* __restrict__ cf)
{
    __half2 hv[8];
    const uint4* q = (const uint4*)p;
    *(uint4*)&hv[0] = q[0];
    *(uint4*)&hv[4] = q[1];
    float s = 0.f;
    #pragma unroll
    for (int i = 0; i < 8; ++i) {
        float2 f = __half22float2(hv[i]);
        s = fmaf(f.x, cf[2 * i + 0], s);
        s = fmaf(f.y, cf[2 * i + 1], s);
    }
    return s;
}

// ---------------------------------------------------------------------------
// Main fused kernel: projection + bilinear + channel-dot + view sum.
// One thread per output element (d, h, w). curT (HW,C) fp32, srcT (V,HW,C) fp16.
// ---------------------------------------------------------------------------
__global__ __launch_bounds__(256) void cost_volume_f16_kernel(
    const float* __restrict__ curT,
    const __half* __restrict__ srcT,
    const float* __restrict__ extr,   // (V,4,4)
    const float* __restrict__ Ks,     // (V,4,4)
    const float* __restrict__ invK,   // (4,4)
    const float* __restrict__ min_d,
    const float* __restrict__ max_d,
    float* __restrict__ out)          // (D,HW)
{
    __shared__ float P_s[VV * 12];
    {
        int t = threadIdx.x;
        if (t < VV * 12) {
            int v   = t / 12;
            int r   = (t % 12) / 4;
            int col = t % 4;
            float s = 0.f;
            #pragma unroll
            for (int k = 0; k < 4; ++k)
                s += Ks[v * 16 + r * 4 + k] * extr[v * 16 + k * 4 + col];
            P_s[t] = s;
        }
    }
    __syncthreads();

    int tid = blockIdx.x * blockDim.x + threadIdx.x;
    if (tid >= DD * HW) return;
    int d  = tid / HW;
    int hw = tid - d * HW;
    int h  = hw / WW;
    int w  = hw - h * WW;

    float px = (float)w + 0.5f, py = (float)h + 0.5f;
    float rx = invK[0] * px + invK[1] * py + invK[2];
    float ry = invK[4] * px + invK[5] * py + invK[6];
    float rz = invK[8] * px + invK[9] * py + invK[10];

    float inv_min = 1.f / min_d[0];
    float inv_max = 1.f / max_d[0];
    float depth   = 1.f / (inv_min + (inv_max - inv_min) * ((float)d / (float)(DD - 1)));

    float cf[CC];
    {
        const float4* p = (const float4*)(curT + (size_t)hw * CC);
        #pragma unroll
        for (int i = 0; i < CC / 4; ++i) {
            float4 q = p[i];
            cf[4*i+0] = q.x; cf[4*i+1] = q.y; cf[4*i+2] = q.z; cf[4*i+3] = q.w;
        }
    }

    float acc = 0.f;
    #pragma unroll
    for (int v = 0; v < VV; ++v) {
        const float* P = &P_s[v * 12];
        float cx = depth * (P[0] * rx + P[1] * ry + P[2]  * rz) + P[3];
        float cy = depth * (P[4] * rx + P[5] * ry + P[6]  * rz) + P[7];
        float cz = depth * (P[8] * rx + P[9] * ry + P[10] * rz) + P[11];
        if (cz > 0.f) {
            float iz = 1.f / (cz + EPSF);
            float x = cx * iz - 0.5f;
            float y = cy * iz - 0.5f;
            float x0f = floorf(x), y0f = floorf(y);
            float fx = x - x0f, fy = y - y0f;
            float x1f = x0f + 1.f, y1f = y0f + 1.f;
            int ix0 = (int)fminf(fmaxf(x0f, 0.f), (float)(WW - 1));
            int ix1 = (int)fminf(fmaxf(x1f, 0.f), (float)(WW - 1));
            int iy0 = (int)fminf(fmaxf(y0f, 0.f), (float)(HH - 1));
            int iy1 = (int)fminf(fmaxf(y1f, 0.f), (float)(HH - 1));
            bool vx0 = (x0f >= 0.f) && (x0f < (float)WW);
            bool vx1 = (x1f >= 0.f) && (x1f < (float)WW);
            bool vy0 = (y0f >= 0.f) && (y0f < (float)HH);
            bool vy1 = (y1f >= 0.f) && (y1f < (float)HH);
            float w00 = (vx0 && vy0) ? (1.f - fx) * (1.f - fy) : 0.f;
            float w01 = (vx1 && vy0) ? fx * (1.f - fy) : 0.f;
            float w10 = (vx0 && vy1) ? (1.f - fx) * fy : 0.f;
            float w11 = (vx1 && vy1) ? fx * fy : 0.f;

            const __half* base = srcT + (size_t)v * HW * CC;
            float d00 = tap_dot16(base + (size_t)(iy0 * WW + ix0) * CC, cf);
            float d01 = tap_dot16(base + (size_t)(iy0 * WW + ix1) * CC, cf);
            float d10 = tap_dot16(base + (size_t)(iy1 * WW + ix0) * CC, cf);
            float d11 = tap_dot16(base + (size_t)(iy1 * WW + ix1) * CC, cf);

            acc += w00 * d00 + w01 * d01 + w10 * d10 + w11 * d11;
        }
    }
    out[tid] = acc;
}

// ---------------------------------------------------------------------------
// Fallback (no workspace): original-layout fp32 gather.
// ---------------------------------------------------------------------------
__global__ __launch_bounds__(256) void cost_volume_fallback_kernel(
    const float* __restrict__ curF,   // (C,HW)
    const float* __restrict__ srcF,   // (V,C,HW)
    const float* __restrict__ extr,
    const float* __restrict__ Ks,
    const float* __restrict__ invK,
    const float* __restrict__ min_d,
    const float* __restrict__ max_d,
    float* __restrict__ out)
{
    __shared__ float P_s[VV * 12];
    {
        int t = threadIdx.x;
        if (t < VV * 12) {
            int v   = t / 12;
            int r   = (t % 12) / 4;
            int col = t % 4;
            float s = 0.f;
            #pragma unroll
            for (int k = 0; k < 4; ++k)
                s += Ks[v * 16 + r * 4 + k] * extr[v * 16 + k * 4 + col];
            P_s[t] = s;
        }
    }
    __syncthreads();

    int tid = blockIdx.x * blockDim.x + threadIdx.x;
    if (tid >= DD * HW) return;
    int d  = tid / HW;
    int hw = tid - d * HW;
    int h  = hw / WW;
    int w  = hw - h * WW;

    float px = (float)w + 0.5f, py = (float)h + 0.5f;
    float rx = invK[0] * px + invK[1] * py + invK[2];
    float ry = invK[4] * px + invK[5] * py + invK[6];
    float rz = invK[8] * px + invK[9] * py + invK[10];

    float inv_min = 1.f / min_d[0];
    float inv_max = 1.f / max_d[0];
    float depth   = 1.f / (inv_min + (inv_max - inv_min) * ((float)d / (float)(DD - 1)));

    float cf[CC];
    #pragma unroll
    for (int c = 0; c < CC; ++c) cf[c] = curF[c * HW + hw];

    float acc = 0.f;
    #pragma unroll
    for (int v = 0; v < VV; ++v) {
        const float* P = &P_s[v * 12];
        float cx = depth * (P[0] * rx + P[1] * ry + P[2]  * rz) + P[3];
        float cy = depth * (P[4] * rx + P[5] * ry + P[6]  * rz) + P[7];
        float cz = depth * (P[8] * rx + P[9] * ry + P[10] * rz) + P[11];
        if (cz > 0.f) {
            float iz = 1.f / (cz + EPSF);
            float x = cx * iz - 0.5f;
            float y = cy * iz - 0.5f;
            float x0f = floorf(x), y0f = floorf(y);
            float fx = x - x0f, fy = y - y0f;
            float x1f = x0f + 1.f, y1f = y0f + 1.f;
            int ix0 = (int)fminf(fmaxf(x0f, 0.f), (float)(WW - 1));
            int ix1 = (int)fminf(fmaxf(x1f, 0.f), (float)(WW - 1));
            int iy0 = (int)fminf(fmaxf(y0f, 0.f), (float)(HH - 1));
            int iy1 = (int)fminf(fmaxf(y1f, 0.f), (float)(HH - 1));
            bool vx0 = (x0f >= 0.f) && (x0f < (float)WW);
            bool vx1 = (x1f >= 0.f) && (x1f < (float)WW);
            bool vy0 = (y0f >= 0.f) && (y0f < (float)HH);
            bool vy1 = (y1f >= 0.f) && (y1f < (float)HH);
            float w00 = (vx0 && vy0) ? (1.f - fx) * (1.f - fy) : 0.f;
            float w01 = (vx1 && vy0) ? fx * (1.f - fy) : 0.f;
            float w10 = (vx0 && vy1) ? (1.f - fx) * fy : 0.f;
            float w11 = (vx1 && vy1) ? fx * fy : 0.f;

            float d00 = 0.f, d01 = 0.f, d10 = 0.f, d11 = 0.f;
            int b = v * CC * HW;
            int i00 = iy0 * WW + ix0, i01 = iy0 * WW + ix1;
            int i10 = iy1 * WW + ix0, i11 = iy1 * WW + ix1;
            #pragma unroll
            for (int c = 0; c < CC; ++c) {
                const float* fc = srcF + b + c * HW;
                d00 += fc[i00] * cf[c];
                d01 += fc[i01] * cf[c];
                d10 += fc[i10] * cf[c];
                d11 += fc[i11] * cf[c];
            }
            acc += w00 * d00 + w01 * d01 + w10 * d10 + w11 * d11;
        }
    }
    out[tid] = acc;
}

extern "C" void kernel_launch(void* const* d_in, const int* in_sizes, int n_in,
                              void* d_out, int out_size, void* d_ws, size_t ws_size,
                              hipStream_t stream) {
    const float* cur  = (const float*)d_in[0];
    const float* src  = (const float*)d_in[1];
    const float* extr = (const float*)d_in[2];
    const float* Ks   = (const float*)d_in[3];
    const float* invK = (const float*)d_in[4];
    const float* mind = (const float*)d_in[5];
    const float* maxd = (const float*)d_in[6];
    float* out = (float*)d_out;

    const size_t need = (size_t)VV * HW * CC * sizeof(__half)
                      + (size_t)HW * CC * sizeof(float);
    const int n_out  = DD * HW;
    const int blocks = (n_out + 255) / 256;

    if (ws_size >= need) {
        __half* srcT = (__half*)d_ws;
        float*  curT = (float*)(srcT + (size_t)VV * HW * CC);
        const int total = VV * HW + HW;
        cv_pack_kernel<<<(total + 255) / 256, 256, 0, stream>>>(src, cur, srcT, curT);
        cost_volume_f16_kernel<<<blocks, 256, 0, stream>>>(
            curT, srcT, extr, Ks, invK, mind, maxd, out);
    } else {
        cost_volume_fallback_kernel<<<blocks, 256, 0, stream>>>(
            cur, src, extr, Ks, invK, mind, maxd, out);
    }
}

// Round 3
// 75.895 us; speedup vs baseline: 1.2463x; 1.0533x over previous
//
#include <hip/hip_runtime.h>
#include <hip/hip_fp16.h>

#define HH 64
#define WW 96
#define DD 64
#define VV 4
#define CC 16
#define HW (HH*WW)
#define EPSF 1e-8f

typedef _Float16 half2_t __attribute__((ext_vector_type(2)));

#if defined(__has_builtin)
#if __has_builtin(__builtin_amdgcn_fdot2)
#define HAVE_FDOT2 1
#endif
#endif

__device__ __forceinline__ float fdot2_acc(half2_t a, half2_t b, float c) {
#ifdef HAVE_FDOT2
    return __builtin_amdgcn_fdot2(a, b, c, false);
#else
    return c + (float)a.x * (float)b.x + (float)a.y * (float)b.y;
#endif
}

// ---------------------------------------------------------------------------
// Pack kernel: src (V,C,HW) fp32 -> srcT (V,HW,C) fp16
//              cur (C,HW)  fp32 -> curT (HW,C)   fp16
// One thread per pixel: channel reads coalesced across lanes, 32B packed write.
// ---------------------------------------------------------------------------
__global__ __launch_bounds__(256) void cv_pack_kernel(
    const float* __restrict__ src, const float* __restrict__ cur,
    __half* __restrict__ srcT, __half* __restrict__ curT)
{
    int tid = blockIdx.x * blockDim.x + threadIdx.x;
    if (tid < VV * HW) {
        int v  = tid / HW;
        int hw = tid - v * HW;
        unsigned short pk[CC];
        #pragma unroll
        for (int c = 0; c < CC; ++c) {
            float f = src[(size_t)v * CC * HW + c * HW + hw];
            pk[c] = __half_as_ushort(__float2half(f));
        }
        uint4* dst = (uint4*)(srcT + (size_t)tid * CC);
        dst[0] = *(uint4*)&pk[0];
        dst[1] = *(uint4*)&pk[8];
    } else {
        int hw = tid - VV * HW;
        if (hw < HW) {
            unsigned short pk[CC];
            #pragma unroll
            for (int c = 0; c < CC; ++c) {
                float f = cur[c * HW + hw];
                pk[c] = __half_as_ushort(__float2half(f));
            }
            uint4* dst = (uint4*)(curT + (size_t)hw * CC);
            dst[0] = *(uint4*)&pk[0];
            dst[1] = *(uint4*)&pk[8];
        }
    }
}

// 32B fp16 tap: 8 x v_dot2_f32_f16 against fp16 cf, fp32 accumulate
__device__ __forceinline__ float tap_dot16(const __half* __restrict__ p,
                                           const half2_t* __restrict__ cf2)
{
    half2_t hv[8];
    const uint4* q = (const uint4*)p;
    *(uint4*)&hv[0] = q[0];
    *(uint4*)&hv[4] = q[1];
    float s = 0.f;
    #pragma unroll
    for (int i = 0; i < 8; ++i)
        s = fdot2_acc(hv[i], cf2[i], s);
    return s;
}

// ---------------------------------------------------------------------------
// Main fused kernel: projection + bilinear + channel-dot + view sum.
// One thread per output element (d, h, w). curT (HW,C) fp16, srcT (V,HW,C) fp16.
// ---------------------------------------------------------------------------
__global__ __launch_bounds__(256) void cost_volume_f16_kernel(
    const __half* __restrict__ curT,
    const __half* __restrict__ srcT,
    const float* __restrict__ extr,   // (V,4,4)
    const float* __restrict__ Ks,     // (V,4,4)
    const float* __restrict__ invK,   // (4,4)
    const float* __restrict__ min_d,
    const float* __restrict__ max_d,
    float* __restrict__ out)          // (D,HW)
{
    __shared__ float P_s[VV * 12];
    {
        int t = threadIdx.x;
        if (t < VV * 12) {
            int v   = t / 12;
            int r   = (t % 12) / 4;
            int col = t % 4;
            float s = 0.f;
            #pragma unroll
            for (int k = 0; k < 4; ++k)
                s += Ks[v * 16 + r * 4 + k] * extr[v * 16 + k * 4 + col];
            P_s[t] = s;
        }
    }
    __syncthreads();

    int tid = blockIdx.x * blockDim.x + threadIdx.x;
    if (tid >= DD * HW) return;
    int d  = tid / HW;
    int hw = tid - d * HW;
    int h  = hw / WW;
    int w  = hw - h * WW;

    float px = (float)w + 0.5f, py = (float)h + 0.5f;
    float rx = invK[0] * px + invK[1] * py + invK[2];
    float ry = invK[4] * px + invK[5] * py + invK[6];
    float rz = invK[8] * px + invK[9] * py + invK[10];

    float inv_min = 1.f / min_d[0];
    float inv_max = 1.f / max_d[0];
    float depth   = 1.f / (inv_min + (inv_max - inv_min) * ((float)d / (float)(DD - 1)));

    half2_t cf2[8];
    {
        const uint4* p = (const uint4*)(curT + (size_t)hw * CC);
        *(uint4*)&cf2[0] = p[0];
        *(uint4*)&cf2[4] = p[1];
    }

    float acc = 0.f;
    #pragma unroll
    for (int v = 0; v < VV; ++v) {
        const float* P = &P_s[v * 12];
        float cx = depth * (P[0] * rx + P[1] * ry + P[2]  * rz) + P[3];
        float cy = depth * (P[4] * rx + P[5] * ry + P[6]  * rz) + P[7];
        float cz = depth * (P[8] * rx + P[9] * ry + P[10] * rz) + P[11];
        if (cz > 0.f) {
            float iz = 1.f / (cz + EPSF);
            float x = cx * iz - 0.5f;
            float y = cy * iz - 0.5f;
            float x0f = floorf(x), y0f = floorf(y);
            float fx = x - x0f, fy = y - y0f;
            float x1f = x0f + 1.f, y1f = y0f + 1.f;
            int ix0 = (int)fminf(fmaxf(x0f, 0.f), (float)(WW - 1));
            int ix1 = (int)fminf(fmaxf(x1f, 0.f), (float)(WW - 1));
            int iy0 = (int)fminf(fmaxf(y0f, 0.f), (float)(HH - 1));
            int iy1 = (int)fminf(fmaxf(y1f, 0.f), (float)(HH - 1));
            bool vx0 = (x0f >= 0.f) && (x0f < (float)WW);
            bool vx1 = (x1f >= 0.f) && (x1f < (float)WW);
            bool vy0 = (y0f >= 0.f) && (y0f < (float)HH);
            bool vy1 = (y1f >= 0.f) && (y1f < (float)HH);
            float w00 = (vx0 && vy0) ? (1.f - fx) * (1.f - fy) : 0.f;
            float w01 = (vx1 && vy0) ? fx * (1.f - fy) : 0.f;
            float w10 = (vx0 && vy1) ? (1.f - fx) * fy : 0.f;
            float w11 = (vx1 && vy1) ? fx * fy : 0.f;

            const __half* base = srcT + (size_t)v * HW * CC;
            float d00 = tap_dot16(base + (size_t)(iy0 * WW + ix0) * CC, cf2);
            float d01 = tap_dot16(base + (size_t)(iy0 * WW + ix1) * CC, cf2);
            float d10 = tap_dot16(base + (size_t)(iy1 * WW + ix0) * CC, cf2);
            float d11 = tap_dot16(base + (size_t)(iy1 * WW + ix1) * CC, cf2);

            acc += w00 * d00 + w01 * d01 + w10 * d10 + w11 * d11;
        }
    }
    out[tid] = acc;
}

// ---------------------------------------------------------------------------
// Fallback (no workspace): original-layout fp32 gather.
// ---------------------------------------------------------------------------
__global__ __launch_bounds__(256) void cost_volume_fallback_kernel(
    const float* __restrict__ curF,   // (C,HW)
    const float* __restrict__ srcF,   // (V,C,HW)
    const float* __restrict__ extr,
    const float* __restrict__ Ks,
    const float* __restrict__ invK,
    const float* __restrict__ min_d,
    const float* __restrict__ max_d,
    float* __restrict__ out)
{
    __shared__ float P_s[VV * 12];
    {
        int t = threadIdx.x;
        if (t < VV * 12) {
            int v   = t / 12;
            int r   = (t % 12) / 4;
            int col = t % 4;
            float s = 0.f;
            #pragma unroll
            for (int k = 0; k < 4; ++k)
                s += Ks[v * 16 + r * 4 + k] * extr[v * 16 + k * 4 + col];
            P_s[t] = s;
        }
    }
    __syncthreads();

    int tid = blockIdx.x * blockDim.x + threadIdx.x;
    if (tid >= DD * HW) return;
    int d  = tid / HW;
    int hw = tid - d * HW;
    int h  = hw / WW;
    int w  = hw - h * WW;

    float px = (float)w + 0.5f, py = (float)h + 0.5f;
    float rx = invK[0] * px + invK[1] * py + invK[2];
    float ry = invK[4] * px + invK[5] * py + invK[6];
    float rz = invK[8] * px + invK[9] * py + invK[10];

    float inv_min = 1.f / min_d[0];
    float inv_max = 1.f / max_d[0];
    float depth   = 1.f / (inv_min + (inv_max - inv_min) * ((float)d / (float)(DD - 1)));

    float cf[CC];
    #pragma unroll
    for (int c = 0; c < CC; ++c) cf[c] = curF[c * HW + hw];

    float acc = 0.f;
    #pragma unroll
    for (int v = 0; v < VV; ++v) {
        const float* P = &P_s[v * 12];
        float cx = depth * (P[0] * rx + P[1] * ry + P[2]  * rz) + P[3];
        float cy = depth * (P[4] * rx + P[5] * ry + P[6]  * rz) + P[7];
        float cz = depth * (P[8] * rx + P[9] * ry + P[10] * rz) + P[11];
        if (cz > 0.f) {
            float iz = 1.f / (cz + EPSF);
            float x = cx * iz - 0.5f;
            float y = cy * iz - 0.5f;
            float x0f = floorf(x), y0f = floorf(y);
            float fx = x - x0f, fy = y - y0f;
            float x1f = x0f + 1.f, y1f = y0f + 1.f;
            int ix0 = (int)fminf(fmaxf(x0f, 0.f), (float)(WW - 1));
            int ix1 = (int)fminf(fmaxf(x1f, 0.f), (float)(WW - 1));
            int iy0 = (int)fminf(fmaxf(y0f, 0.f), (float)(HH - 1));
            int iy1 = (int)fminf(fmaxf(y1f, 0.f), (float)(HH - 1));
            bool vx0 = (x0f >= 0.f) && (x0f < (float)WW);
            bool vx1 = (x1f >= 0.f) && (x1f < (float)WW);
            bool vy0 = (y0f >= 0.f) && (y0f < (float)HH);
            bool vy1 = (y1f >= 0.f) && (y1f < (float)HH);
            float w00 = (vx0 && vy0) ? (1.f - fx) * (1.f - fy) : 0.f;
            float w01 = (vx1 && vy0) ? fx * (1.f - fy) : 0.f;
            float w10 = (vx0 && vy1) ? (1.f - fx) * fy : 0.f;
            float w11 = (vx1 && vy1) ? fx * fy : 0.f;

            float d00 = 0.f, d01 = 0.f, d10 = 0.f, d11 = 0.f;
            int b = v * CC * HW;
            int i00 = iy0 * WW + ix0, i01 = iy0 * WW + ix1;
            int i10 = iy1 * WW + ix0, i11 = iy1 * WW + ix1;
            #pragma unroll
            for (int c = 0; c < CC; ++c) {
                const float* fc = srcF + b + c * HW;
                d00 += fc[i00] * cf[c];
                d01 += fc[i01] * cf[c];
                d10 += fc[i10] * cf[c];
                d11 += fc[i11] * cf[c];
            }
            acc += w00 * d00 + w01 * d01 + w10 * d10 + w11 * d11;
        }
    }
    out[tid] = acc;
}

extern "C" void kernel_launch(void* const* d_in, const int* in_sizes, int n_in,
                              void* d_out, int out_size, void* d_ws, size_t ws_size,
                              hipStream_t stream) {
    const float* cur  = (const float*)d_in[0];
    const float* src  = (const float*)d_in[1];
    const float* extr = (const float*)d_in[2];
    const float* Ks   = (const float*)d_in[3];
    const float* invK = (const float*)d_in[4];
    const float* mind = (const float*)d_in[5];
    const float* maxd = (const float*)d_in[6];
    float* out = (float*)d_out;

    const size_t need = (size_t)(VV * HW * CC + HW * CC) * sizeof(__half);
    const int n_out  = DD * HW;
    const int blocks = (n_out + 255) / 256;

    if (ws_size >= need) {
        __half* srcT = (__half*)d_ws;
        __half* curT = srcT + (size_t)VV * HW * CC;
        const int total = VV * HW + HW;
        cv_pack_kernel<<<(total + 255) / 256, 256, 0, stream>>>(src, cur, srcT, curT);
        cost_volume_f16_kernel<<<blocks, 256, 0, stream>>>(
            curT, srcT, extr, Ks, invK, mind, maxd, out);
    } else {
        cost_volume_fallback_kernel<<<blocks, 256, 0, stream>>>(
            cur, src, extr, Ks, invK, mind, maxd, out);
    }
}